// Round 15
// baseline (203.818 us; speedup 1.0000x reference)
//
#include <hip/hip_runtime.h>

typedef unsigned short u16;
typedef unsigned int u32;
typedef __attribute__((ext_vector_type(8))) short short8;
typedef __attribute__((ext_vector_type(4))) float f32x4;

#define BB 8
#define CCH 256
#define HH 64
#define WW 64
#define HP 66
#define NPOS 4096
#define KTOT 2304

// ---- ws layout (bytes) ----
#define XT_BYTES   17842176ull                 // bf16 [8][66][66][256]
#define W2R_OFF    17842176ull                 // bf16 [256][2304] row-major
#define WOFF2_OFF  19021824ull                 // bf16 [32][2304] (rows 18..31 zero)
#define WS_MIN     19169280ull                 // P/off2 buffers no longer needed (fused)

__device__ __forceinline__ u16 f2bf(float f) {
    union { float f; u32 u; } v; v.f = f;
    u32 r = v.u + 0x7FFFu + ((v.u >> 16) & 1u);
    return (u16)(r >> 16);
}
__device__ __forceinline__ u32 pk2(float a, float b) {
    return (u32)f2bf(a) | ((u32)f2bf(b) << 16);
}
// single-instruction packed f32->bf16 (RNE, same bits as pk2 for finite values)
__device__ __forceinline__ u32 cvtpk(float lo, float hi) {
    u32 r;
    asm("v_cvt_pk_bf16_f32 %0, %1, %2" : "=v"(r) : "v"(lo), "v"(hi));
    return r;
}
__device__ __forceinline__ void bf2x2(u32 p, float& a, float& b) {
    union { u32 u; float f; } va, vb;
    va.u = p << 16; vb.u = p & 0xffff0000u;
    a = va.f; b = vb.f;
}
// async global->LDS, 16B per lane; LDS dest = wave-uniform base + lane*16
__device__ __forceinline__ void ldg_lds16(const u16* g, u16* l) {
    __builtin_amdgcn_global_load_lds((const __attribute__((address_space(1))) u32*)g,
                                     (__attribute__((address_space(3))) u32*)l, 16, 0, 0);
}

// ---- K_PRE: weight-reorder + border-zero + transpose (R13-verified).
// Blocks: [0,256) w-reorder | [256,288) Woff2 rows | [288,808) border | [808,2856) transpose.
__global__ __launch_bounds__(256) void k_pre(const float* __restrict__ w, const float* __restrict__ w_off,
                                             const float* __restrict__ x,
                                             u16* __restrict__ W2r, u16* __restrict__ Woff2,
                                             u16* __restrict__ xT) {
    __shared__ __align__(16) float SH[4608];   // prep uses 2304; transpose uses 64x72
    int bx = blockIdx.x;
    int t = threadIdx.x;
    if (bx < 256) {
        int o = bx;
        const float* src = w + (size_t)o * 2304;
#pragma unroll
        for (int j = 0; j < 9; ++j) SH[j * 256 + t] = src[j * 256 + t];
        __syncthreads();
        u16* dst = W2r + (size_t)o * 2304;
#pragma unroll
        for (int k = 0; k < 9; ++k) dst[k * 256 + t] = f2bf(SH[t * 9 + k]);   // stride-9: conflict-free
    } else if (bx < 288) {
        int o2 = bx - 256;                      // one block per Woff2 row
        if (o2 < 18) {
            const float* src = w_off + (size_t)o2 * 2304;
#pragma unroll
            for (int j = 0; j < 9; ++j) SH[j * 256 + t] = src[j * 256 + t];
            __syncthreads();
#pragma unroll
            for (int k = 0; k < 9; ++k) Woff2[(size_t)o2 * 2304 + k * 256 + t] = f2bf(SH[t * 9 + k]);
        } else {
#pragma unroll
            for (int k = 0; k < 9; ++k) Woff2[(size_t)o2 * 2304 + k * 256 + t] = 0;
        }
    } else if (bx < 808) {
        // border zero: 2080 positions, 4 per block (64 lanes each)
        int idx = (bx - 288) * 4 + (t >> 6);
        int b = idx / 260, m = idx - b * 260;
        int y, xx;
        if (m < 66)       { y = 0;  xx = m; }
        else if (m < 132) { y = 65; xx = m - 66; }
        else if (m < 196) { y = m - 132 + 1; xx = 0; }
        else              { y = m - 196 + 1; xx = 65; }
        u16* p = xT + ((size_t)(b * HP + y) * HP + xx) * CCH + (t & 63) * 4;
        uint2 zz; zz.x = 0; zz.y = 0;
        *(uint2*)p = zz;
    } else {
        int idx = bx - 808;               // 2048 transpose tiles
        int b = idx & 7;                  // XCD pin
        int r = idx >> 3;
        int y = r & 63, c0 = (r >> 6) * 64;
        {
            int rrow = t >> 4, rlane = t & 15;   // 16 lanes span one 256B row; 4 rows/wave
#pragma unroll
            for (int k = 0; k < 4; ++k) {
                int i = rrow + k * 16;           // channel 0..63
                const float* src = x + (((size_t)(b * CCH + c0 + i) * HH + y) * WW) + rlane * 4;
                float4 v = *(const float4*)src;
                *(float4*)&SH[i * 72 + rlane * 4] = v;
            }
        }
        __syncthreads();
        {
            int xc = t >> 2, cs = t & 3;   // x-position xc, 16-channel segment cs
            u16* dst = xT + (((size_t)(b * HP + y + 1) * HP) + (xc + 1)) * CCH + c0 + cs * 16;
            u32 p[8];
#pragma unroll
            for (int j = 0; j < 8; ++j)
                p[j] = pk2(SH[(cs * 16 + 2 * j) * 72 + xc], SH[(cs * 16 + 2 * j + 1) * 72 + xc]);
            uint4 d0, d1;
            d0.x = p[0]; d0.y = p[1]; d0.z = p[2]; d0.w = p[3];
            d1.x = p[4]; d1.y = p[5]; d1.z = p[6]; d1.w = p[7];
            *(uint4*)dst = d0;
            *(uint4*)(dst + 8) = d1;
        }
    }
}

// ---- K4 (fused EVERYTHING): prologue computes this block's off2 slice (18x128, K=2304
// mini-GEMM, verified k_offconv fragment conventions) into LDS OFF[18][128]; then the
// EXACT R4/R7-verified pipelined main loop runs, reading fnext from OFF instead of global.
// k_offconv + k_reduce kernels and P/off2 buffers are DELETED.
// vmcnt ledger (re-verified, F now LDS): per step outstanding = A(4)+G(8)=12;
// top vmcnt(8) drains A(gs), pre-blend vmcnt(4) drains G(gs-1). Same constants as R4.
__global__ __launch_bounds__(512, 2) void k_gemm(const u16* __restrict__ xT,
                                                 const u16* __restrict__ Woff2,
                                                 const float* __restrict__ b_off,
                                                 const u16* __restrict__ W2r,
                                                 const float* __restrict__ bias,
                                                 float* __restrict__ out) {
    __shared__ __align__(16) u16 AS[2][16384];   // 2 x [256 row][64 k] swizzled chunks, 64KB
    __shared__ __align__(16) u16 BSF[128 * 264]; // [128 pos][256 k + 8 pad], 67.6KB
    __shared__ __align__(16) float OFF[18 * 128];// off2 slice (dy/dx interleaved by o), 9.2KB
    int b = blockIdx.x;                          // batch; linear%8==b -> XCD-pinned, xT L2-hot
    int pos0 = blockIdx.z * 128;
    int t = threadIdx.x, lane = t & 63, wv = t >> 6;   // wv 0..7
    int wr = wv >> 1, wc = wv & 1;                     // 4M x 2N wave grid

    int srow = lane >> 3;
    int sw8 = ((lane & 7) ^ srow) << 3;          // A-side pre-swizzled global chunk
    const u16* pA = W2r;

    int brow0 = t >> 3;                          // 0..63
    int bcl = (t & 7) << 3;                      // 0..56 (u16 elems)
    int bbase = b * HP * HP;

    f32x4 acc[4][4];
    f32x4 z = {0.f, 0.f, 0.f, 0.f};
#pragma unroll
    for (int i = 0; i < 4; ++i)
#pragma unroll
        for (int j = 0; j < 4; ++j) acc[i][j] = z;

    int m = lane & 15, q = lane >> 4, key = lane & 7;

    // ---- P0: offset-conv mini-GEMM -> OFF. Each wave owns 16 positions (wv*16..+15).
    // Fragment conventions = verified k_offconv: A row o = lane&15 (+16), k = q*8+e;
    // B n = lane&15 (pos), k = q*8+e; C/D col = lane&15 (pos), row = q*4+r (o).
    {
        int pl = wv * 16 + m;                    // this lane's pos column
        int posg = pos0 + pl;
        int yy = posg >> 6, xx = posg & 63;
        f32x4 pacc0 = z, pacc1 = z;
        const u16* apb = Woff2 + (size_t)m * KTOT + q * 8;
        for (int g2 = 0; g2 < 72; ++g2) {
            int tap = g2 >> 3;
            int ky = tap / 3, kx = tap - (tap / 3) * 3;
            int ch0 = (g2 & 7) * 32;
            const u16* bp = xT + ((size_t)(bbase + (yy + ky) * HP) + (xx + kx)) * CCH + ch0 + q * 8;
            short8 bf = *(const short8*)bp;
            short8 a0 = *(const short8*)(apb + (g2 << 5));
            short8 a1 = *(const short8*)(apb + (size_t)16 * KTOT + (g2 << 5));
            pacc0 = __builtin_amdgcn_mfma_f32_16x16x32_bf16(a0, bf, pacc0, 0, 0, 0);
            pacc1 = __builtin_amdgcn_mfma_f32_16x16x32_bf16(a1, bf, pacc1, 0, 0, 0);
        }
#pragma unroll
        for (int r = 0; r < 4; ++r) {
            int o0 = q * 4 + r;                  // 0..15, all valid
            OFF[o0 * 128 + pl] = pacc0[r] + b_off[o0];
            int o1 = 16 + q * 4 + r;             // 16..31, only 16/17 valid
            if (o1 < 18) OFF[o1 * 128 + pl] = pacc1[r] + b_off[o1];
        }
        asm volatile("s_waitcnt lgkmcnt(0)" ::: "memory");
        __builtin_amdgcn_s_barrier();            // OFF visible to all waves
    }

    // pipeline state
    const u16* gp[2][4];
    float wt[2][4];
    float2 fnext[2];
    uint4 gv[8];

    auto ldOff = [&](int tap) {                  // fnext <- OFF (LDS)
        fnext[0].x = OFF[(2 * tap) * 128 + brow0];
        fnext[0].y = OFF[(2 * tap + 1) * 128 + brow0];
        fnext[1].x = OFF[(2 * tap) * 128 + brow0 + 64];
        fnext[1].y = OFF[(2 * tap + 1) * 128 + brow0 + 64];
    };
    auto computeState = [&](int tap) {
#pragma unroll
        for (int ii = 0; ii < 2; ++ii) {
            int pos = pos0 + brow0 + (ii << 6);
            int y = pos >> 6, x = pos & 63;
            int ky = tap / 3, kx = tap - (tap / 3) * 3;
            float pyf = (float)(y - 1 + ky) + fnext[ii].x;
            float pxf = (float)(x - 1 + kx) + fnext[ii].y;
            float y0f = floorf(pyf), x0f = floorf(pxf);
            int y0 = (int)y0f, x0 = (int)x0f;
            int y1 = y0 + 1, x1 = x0 + 1;
            float wy1 = pyf - y0f, wy0 = 1.f - wy1;
            float wx1 = pxf - x0f, wx0 = 1.f - wx1;
            bool vy0 = (y0 >= 0) & (y0 < HH), vy1 = (y1 >= 0) & (y1 < HH);
            bool vx0 = (x0 >= 0) & (x0 < WW), vx1 = (x1 >= 0) & (x1 < WW);
            int yc0 = min(max(y0, 0), HH - 1), yc1 = min(max(y1, 0), HH - 1);
            int xc0 = min(max(x0, 0), WW - 1), xc1 = min(max(x1, 0), WW - 1);
            wt[ii][0] = (vy0 & vx0) ? wy0 * wx0 : 0.f;
            wt[ii][1] = (vy0 & vx1) ? wy0 * wx1 : 0.f;
            wt[ii][2] = (vy1 & vx0) ? wy1 * wx0 : 0.f;
            wt[ii][3] = (vy1 & vx1) ? wy1 * wx1 : 0.f;
            gp[ii][0] = xT + (size_t)(bbase + (yc0 + 1) * HP + xc0 + 1) * CCH + bcl;
            gp[ii][1] = xT + (size_t)(bbase + (yc0 + 1) * HP + xc1 + 1) * CCH + bcl;
            gp[ii][2] = xT + (size_t)(bbase + (yc1 + 1) * HP + xc0 + 1) * CCH + bcl;
            gp[ii][3] = xT + (size_t)(bbase + (yc1 + 1) * HP + xc1 + 1) * CCH + bcl;
        }
    };
    auto gatherRegion = [&](int rr) {
#pragma unroll
        for (int ii = 0; ii < 2; ++ii)
#pragma unroll
            for (int c = 0; c < 4; ++c)
                gv[ii * 4 + c] = *(const uint4*)(gp[ii][c] + rr * 64);
    };
    auto blendWrite = [&](int rr) {
#pragma unroll
        for (int ii = 0; ii < 2; ++ii) {
            int row = brow0 + (ii << 6);
            float v[8];
#pragma unroll
            for (int dw = 0; dw < 4; ++dw) {
                float a0, b0_, a1, b1_, a2, b2_, a3, b3_;
                bf2x2(((const u32*)&gv[ii * 4 + 0])[dw], a0, b0_);
                bf2x2(((const u32*)&gv[ii * 4 + 1])[dw], a1, b1_);
                bf2x2(((const u32*)&gv[ii * 4 + 2])[dw], a2, b2_);
                bf2x2(((const u32*)&gv[ii * 4 + 3])[dw], a3, b3_);
                v[2 * dw]     = wt[ii][0] * a0 + wt[ii][1] * a1 + wt[ii][2] * a2 + wt[ii][3] * a3;
                v[2 * dw + 1] = wt[ii][0] * b0_ + wt[ii][1] * b1_ + wt[ii][2] * b2_ + wt[ii][3] * b3_;
            }
            uint4 sv;
            sv.x = cvtpk(v[0], v[1]); sv.y = cvtpk(v[2], v[3]);
            sv.z = cvtpk(v[4], v[5]); sv.w = cvtpk(v[6], v[7]);
            *(uint4*)&BSF[row * 264 + rr * 64 + bcl] = sv;
        }
    };
    auto stageA = [&](int gs, int d) {           // A slice for step gs
        int k9 = gs >> 2, cs = gs & 3;
        int koffA = k9 * 256 + cs * 64;
#pragma unroll
        for (int i = 0; i < 4; ++i) {
            int inst = wv * 4 + i;
            int row = inst * 8 + srow;           // 0..255
            ldg_lds16(pA + (size_t)row * KTOT + koffA + sw8, &AS[d][inst * 512]);
        }
    };

    // ---- P1 (original prologue): fill all 4 regions of tap 0; fnext(tap1); issue A(0) ----
    {
        ldOff(0);
        computeState(0);
#pragma unroll
        for (int rr = 0; rr < 4; ++rr) {
            gatherRegion(rr);
            blendWrite(rr);
        }
        ldOff(1);
        stageA(0, 0);
        asm volatile("s_waitcnt lgkmcnt(0)" ::: "memory");   // BSF(tap0) ds_writes flushed
    }

    for (int gs = 0; gs <= 35; ++gs) {
        int t9 = gs >> 2, cs = gs & 3, cur = gs & 1;
        // drain my A(gs) staging loads (oldest in FIFO); keep G(gs-1) in flight
        if (gs >= 1 && gs <= 32) { asm volatile("s_waitcnt vmcnt(8)" ::: "memory"); }
        else                     { asm volatile("s_waitcnt vmcnt(0)" ::: "memory"); }
        __builtin_amdgcn_s_barrier();            // AS[cur]+BSF(region cs) complete; prior readers done

        if (gs < 35) stageA(gs + 1, cur ^ 1);    // AS[cur^1]: last read at gs-1, freed by barrier
        __builtin_amdgcn_sched_barrier(0);       // pin FIFO order: A before G

        // blend gathers issued last iteration -> region (cs+3)&3 (last read at gs-1)
        if (gs >= 1 && gs <= 32) {
            asm volatile("s_waitcnt vmcnt(4)" ::: "memory");  // G(gs-1) landed; A(gs+1) stays in flight
            blendWrite((cs + 3) & 3);
        }
        if (cs == 0 && t9 <= 7) {
            ldOff(t9 + 1);                       // LDS read (free); replaces global off2 prefetch
            computeState(t9 + 1);
        }
        if (gs <= 31) gatherRegion(cs);          // gathers for (tap t9+1, region cs)
        __builtin_amdgcn_sched_barrier(0);       // loads issued before MFMA block

#pragma unroll
        for (int j = 0; j < 2; ++j) {
            int slot8 = (((j * 4 + q) ^ key) << 3);
            int bchunk = (cs * 8 + j * 4 + q) << 3;
            short8 af[4], bfr[4];
#pragma unroll
            for (int ao = 0; ao < 4; ++ao)
                af[ao] = *(const short8*)&AS[cur][(wr * 64 + ao * 16 + m) * 64 + slot8];
#pragma unroll
            for (int bn = 0; bn < 4; ++bn)
                bfr[bn] = *(const short8*)&BSF[(wc * 64 + bn * 16 + m) * 264 + bchunk];
            __builtin_amdgcn_s_setprio(1);
#pragma unroll
            for (int ao = 0; ao < 4; ++ao)
#pragma unroll
                for (int bn = 0; bn < 4; ++bn)
                    acc[ao][bn] = __builtin_amdgcn_mfma_f32_16x16x32_bf16(af[ao], bfr[bn], acc[ao][bn], 0, 0, 0);
            __builtin_amdgcn_s_setprio(0);
        }
        asm volatile("s_waitcnt lgkmcnt(0)" ::: "memory");  // my ds_reads+ds_writes done before next barrier
    }

    // epilogue: bias + sigmoid -> fp32 NCHW
    int nn = lane & 15;
#pragma unroll
    for (int ao = 0; ao < 4; ++ao) {
        int ob = wr * 64 + ao * 16 + q * 4;
#pragma unroll
        for (int bn = 0; bn < 4; ++bn) {
            int pos = pos0 + wc * 64 + bn * 16 + nn;
#pragma unroll
            for (int r = 0; r < 4; ++r) {
                float v = acc[ao][bn][r] + bias[ob + r];
                float sg = 1.0f / (1.0f + __expf(-v));
                out[(size_t)((b * CCH + ob + r) * NPOS) + pos] = sg;
            }
        }
    }
}

extern "C" void kernel_launch(void* const* d_in, const int* in_sizes, int n_in,
                              void* d_out, int out_size, void* d_ws, size_t ws_size,
                              hipStream_t stream) {
    const float* x     = (const float*)d_in[0];
    const float* w_off = (const float*)d_in[1];
    const float* b_off = (const float*)d_in[2];
    const float* w     = (const float*)d_in[3];
    const float* bias  = (const float*)d_in[4];
    float* out = (float*)d_out;

    char* ws = (char*)d_ws;
    u16*    xT    = (u16*)ws;
    u16*    W2r   = (u16*)(ws + W2R_OFF);
    u16*    Woff2 = (u16*)(ws + WOFF2_OFF);

    if (ws_size < WS_MIN) return;

    k_pre<<<2856, 256, 0, stream>>>(w, w_off, x, W2r, Woff2, xT);
    k_gemm<<<dim3(8, 1, 32), 512, 0, stream>>>(xT, Woff2, b_off, W2r, bias, out);
}